// Round 4
// baseline (10191.552 us; speedup 1.0000x reference)
//
#include <hip/hip_runtime.h>
#include <math.h>

#define NB   32    // batch
#define TH   128   // scan steps
#define NL   6     // layers
#define DD   128   // model dim
#define NH   4     // heads
#define DHD  32    // head dim
#define TCAP 128   // max cached tokens
#define D3   384
#define D4   512

// repacked weight unit counts (f16x2 units; unit = (w[2kp][c], w[2kp+1][c]))
#define UQ  (NL * 64 * D3)    // qkv  : 64 kp x 384 c per layer
#define UP  (NL * 64 * DD)    // proj : 64 kp x 128 c
#define UF  (NL * 64 * D4)    // fc   : 64 kp x 512 c
#define UF2 (NL * 256 * DD)   // fc2  : 256 kp x 128 c

typedef _Float16 f16;
typedef _Float16 f16x2 __attribute__((ext_vector_type(2)));
typedef _Float16 f16x4 __attribute__((ext_vector_type(4)));
typedef _Float16 f16x8 __attribute__((ext_vector_type(8)));

// fp32 -> f16, repacked k-pair-interleaved: out2[l, kp, c] = (w[2kp][c], w[2kp+1][c])
__global__ void prep_kernel(const float* __restrict__ qkv, const float* __restrict__ proj,
                            const float* __restrict__ fc,  const float* __restrict__ fc2,
                            f16* __restrict__ out) {
    int u = blockIdx.x * blockDim.x + threadIdx.x;
    const int total = UQ + UP + UF + UF2;
    if (u >= total) return;
    f16x2* o2 = (f16x2*)out;
    const float* M; int NC, rel;
    if (u < UQ)                { M = qkv;  NC = D3; rel = u;            M += (rel / (64 * D3))  * DD * D3; rel %= 64 * D3; }
    else if (u < UQ + UP)      { M = proj; NC = DD; rel = u - UQ;       M += (rel / (64 * DD))  * DD * DD; rel %= 64 * DD; }
    else if (u < UQ + UP + UF) { M = fc;   NC = D4; rel = u - UQ - UP;  M += (rel / (64 * D4))  * DD * D4; rel %= 64 * D4; }
    else                       { M = fc2;  NC = DD; rel = u - UQ - UP - UF; M += (rel / (256 * DD)) * D4 * DD; rel %= 256 * DD; }
    int kp = rel / NC, c = rel % NC;
    f16x2 w; w.x = (f16)M[(2 * kp) * NC + c]; w.y = (f16)M[(2 * kp + 1) * NC + c];
    o2[u] = w;
}

__device__ __forceinline__ float wave_xor_sum(float v) {
    #pragma unroll
    for (int off = 1; off < 64; off <<= 1) v += __shfl_xor(v, off);
    return v;
}
__device__ __forceinline__ float wave_xor_max(float v) {
    #pragma unroll
    for (int off = 1; off < 64; off <<= 1) v = fmaxf(v, __shfl_xor(v, off));
    return v;
}
__device__ __forceinline__ float gelu_tanh(float v) {
    float t = v * v * v;
    return 0.5f * v * (1.f + tanhf(0.7978845608028654f * (v + 0.044715f * t)));
}
// acc[j] += dot2(hp, col j k-pair) for 8 cols from two 16B loads
__device__ __forceinline__ void dot8(float* acc, f16x2 hp, f16x8 wa, f16x8 wb) {
    acc[0] = __builtin_amdgcn_fdot2(hp, (f16x2){wa[0], wa[1]}, acc[0], false);
    acc[1] = __builtin_amdgcn_fdot2(hp, (f16x2){wa[2], wa[3]}, acc[1], false);
    acc[2] = __builtin_amdgcn_fdot2(hp, (f16x2){wa[4], wa[5]}, acc[2], false);
    acc[3] = __builtin_amdgcn_fdot2(hp, (f16x2){wa[6], wa[7]}, acc[3], false);
    acc[4] = __builtin_amdgcn_fdot2(hp, (f16x2){wb[0], wb[1]}, acc[4], false);
    acc[5] = __builtin_amdgcn_fdot2(hp, (f16x2){wb[2], wb[3]}, acc[5], false);
    acc[6] = __builtin_amdgcn_fdot2(hp, (f16x2){wb[4], wb[5]}, acc[6], false);
    acc[7] = __builtin_amdgcn_fdot2(hp, (f16x2){wb[6], wb[7]}, acc[7], false);
}
// LN stats via redundant in-wave reduction (x must be barrier-synced)
__device__ __forceinline__ void ln_stats(const float* x, int lane, float& m, float& rs) {
    float v0 = x[lane], v1 = x[lane + 64];
    float sm = wave_xor_sum(v0 + v1);
    float sq = wave_xor_sum(v0 * v0 + v1 * v1);
    m  = sm * (1.f / DD);
    rs = rsqrtf(sq * (1.f / DD) - m * m + 1e-5f);
}
// build 8 f16 k-pairs of LN'd h for k in [k0, k0+16)
__device__ __forceinline__ void make_h2(f16x2* hp, const float* x, const float* w,
                                        const float* bb, int k0, float m, float rs) {
    #pragma unroll
    for (int t = 0; t < 8; t++) {
        int k = k0 + 2 * t;
        float a = (x[k]     - m) * rs * w[k]     + bb[k];
        float c = (x[k + 1] - m) * rs * w[k + 1] + bb[k + 1];
        hp[t] = (f16x2){(f16)a, (f16)c};
    }
}

__global__ __launch_bounds__(512) void gpt_loop(
    const float* __restrict__ data,  const float* __restrict__ r,
    const float* __restrict__ wte_w, const float* __restrict__ wte_b,
    const float* __restrict__ wpe,
    const float* __restrict__ ln1_w, const float* __restrict__ ln1_b,
    const float* __restrict__ ln2_w, const float* __restrict__ ln2_b,
    const float* __restrict__ qkv_b, const float* __restrict__ proj_b,
    const float* __restrict__ fc_b,  const float* __restrict__ fc2_b,
    const float* __restrict__ lnf_w, const float* __restrict__ lnf_b,
    const float* __restrict__ head_w,const float* __restrict__ head_b,
    const f16* __restrict__ Wall,
    f16* __restrict__ Kc, f16* __restrict__ Vc,
    float* __restrict__ Y)
{
    const int b    = blockIdx.x;
    const int tid  = threadIdx.x;
    const int lane = tid & 63;
    const int wid  = tid >> 6;

    const f16x2* Wq2  = (const f16x2*)Wall;
    const f16x2* Wp2  = Wq2 + UQ;
    const f16x2* Wf2u = Wp2 + UP;
    const f16x2* Wg2  = Wf2u + UF;

    __shared__ float x[DD];
    __shared__ f16   q_lds[DD], o_lds[DD], hm_lds[D4];
    __shared__ float sc[NH][TCAP];
    __shared__ float s_state, u_state;
    __shared__ float c_ln1w[NL][DD], c_ln1b[NL][DD], c_ln2w[NL][DD], c_ln2b[NL][DD];
    __shared__ float c_qkvb[NL][D3], c_projb[NL][DD], c_fcb[NL][D4], c_fc2b[NL][DD];
    __shared__ float c_lnfw[DD], c_lnfb[DD], c_headw[DD], c_wte0[DD], c_wte1[DD], c_wteb[DD];

    const float p0 = data[b * 2 + 0];
    const float p1 = data[b * 2 + 1];
    const float hb = head_b[0];

    f16* Kb = Kc + (size_t)b * NL * TCAP * DD;
    f16* Vb = Vc + (size_t)b * NL * TCAP * DD;

    for (int idx = tid; idx < NL * DD; idx += 512) {
        int l = idx / DD, d = idx % DD;
        c_ln1w[l][d] = ln1_w[idx]; c_ln1b[l][d] = ln1_b[idx];
        c_ln2w[l][d] = ln2_w[idx]; c_ln2b[l][d] = ln2_b[idx];
        c_projb[l][d] = proj_b[idx]; c_fc2b[l][d] = fc2_b[idx];
    }
    for (int idx = tid; idx < NL * D3; idx += 512) c_qkvb[idx / D3][idx % D3] = qkv_b[idx];
    for (int idx = tid; idx < NL * D4; idx += 512) c_fcb[idx / D4][idx % D4] = fc_b[idx];
    if (tid < DD) {
        c_lnfw[tid] = lnf_w[tid]; c_lnfb[tid] = lnf_b[tid]; c_headw[tid] = head_w[tid];
        c_wte0[tid] = wte_w[tid]; c_wte1[tid] = wte_w[DD + tid]; c_wteb[tid] = wte_b[tid];
    }
    if (tid == 0) { s_state = 0.f; u_state = 0.f; }
    __syncthreads();

    for (int i = 0; i < TH; i++) {
        const float s  = s_state;
        const float uu = u_state;
        const float e  = r[b * TH + i] - s;

        if (tid < DD)
            x[tid] = e * c_wte0[tid] + uu * c_wte1[tid] + c_wteb[tid] + wpe[i * DD + tid];
        __syncthreads();

        for (int l = 0; l < NL; l++) {
            // ---- qkv (LN1 fused): waves 0-5, 8 cols x 16 k per thread ----
            f16* Krow = Kb + ((size_t)l * TCAP + i) * DD;
            f16* Vrow = Vb + ((size_t)l * TCAP + i) * DD;
            if (wid < 6) {
                const int cg = lane & 7, ks = lane >> 3;
                const int cb = wid * 64 + cg * 8, k0 = ks * 16, kp0 = ks * 8;
                float m, rs; ln_stats(x, lane, m, rs);
                f16x2 hp[8]; make_h2(hp, x, c_ln1w[l], c_ln1b[l], k0, m, rs);
                const f16x2* W = Wq2 + (size_t)l * (64 * D3);
                float acc[8] = {0,0,0,0,0,0,0,0};
                #pragma unroll
                for (int t = 0; t < 8; t++) {
                    const f16x2* p = W + (size_t)(kp0 + t) * D3 + cb;
                    f16x8 wa = *(const f16x8*)p;
                    f16x8 wb = *(const f16x8*)(p + 4);
                    dot8(acc, hp[t], wa, wb);
                }
                #pragma unroll
                for (int off = 8; off <= 32; off <<= 1) {
                    #pragma unroll
                    for (int j = 0; j < 8; j++) acc[j] += __shfl_xor(acc[j], off);
                }
                if (ks == 0) {
                    f16x8 pk;
                    #pragma unroll
                    for (int j = 0; j < 8; j++) pk[j] = (f16)(acc[j] + c_qkvb[l][cb + j]);
                    if (cb < DD)            *(f16x8*)(q_lds + cb) = pk;
                    else if (cb < 2 * DD)   *(f16x8*)(Krow + (cb - DD)) = pk;
                    else                    *(f16x8*)(Vrow + (cb - 2 * DD)) = pk;
                }
            }
            __syncthreads();

            const f16* Kl = Kb + (size_t)l * TCAP * DD;
            const f16* Vl = Vb + (size_t)l * TCAP * DD;

            // ---- scores + softmax: wave w = head w (dot2 q.k) ----
            if (wid < NH) {
                const int hh = wid;
                const bool ok0 = (lane <= i), ok1 = (lane + 64 <= i);
                const int j0 = ok0 ? lane : i;
                const int j1 = ok1 ? lane + 64 : i;
                const f16x8* K0 = (const f16x8*)(Kl + (size_t)j0 * DD + hh * DHD);
                const f16x8* K1 = (const f16x8*)(Kl + (size_t)j1 * DD + hh * DHD);
                const f16x2* q2 = (const f16x2*)q_lds + hh * 16;
                float d0 = 0.f, d1 = 0.f;
                #pragma unroll
                for (int g = 0; g < 4; g++) {
                    f16x8 ka = K0[g], kb2 = K1[g];
                    #pragma unroll
                    for (int t = 0; t < 4; t++) {
                        f16x2 qp = q2[g * 4 + t];
                        d0 = __builtin_amdgcn_fdot2(qp, (f16x2){ka[2*t], ka[2*t+1]}, d0, false);
                        d1 = __builtin_amdgcn_fdot2(qp, (f16x2){kb2[2*t], kb2[2*t+1]}, d1, false);
                    }
                }
                const float sscale = 0.17677669529663687f;
                float s0 = ok0 ? d0 * sscale : -1e30f;
                float s1 = ok1 ? d1 * sscale : -1e30f;
                float mx = wave_xor_max(fmaxf(s0, s1));
                float e0 = ok0 ? expf(s0 - mx) : 0.f;
                float e1 = ok1 ? expf(s1 - mx) : 0.f;
                float inv = 1.f / wave_xor_sum(e0 + e1);
                sc[hh][lane]      = e0 * inv;
                sc[hh][lane + 64] = e1 * inv;
            }
            __syncthreads();

            // ---- AV: 32 col-quads x 16 j-splits ----
            {
                const int qd = wid * 4 + (lane & 3);
                const int js = lane >> 2;
                const int cb = qd * 4;
                const int hh = cb >> 5;
                const f16* Vp = Vl + cb;
                float a0 = 0.f, a1 = 0.f, a2 = 0.f, a3 = 0.f;
                const int ja = js * 8, jbnd = min(i + 1, js * 8 + 8);
                for (int j = ja; j < jbnd; j++) {
                    f16x4 vv = *(const f16x4*)(Vp + (size_t)j * DD);
                    float p = sc[hh][j];
                    a0 += p * (float)vv[0]; a1 += p * (float)vv[1];
                    a2 += p * (float)vv[2]; a3 += p * (float)vv[3];
                }
                #pragma unroll
                for (int off = 4; off <= 32; off <<= 1) {
                    a0 += __shfl_xor(a0, off); a1 += __shfl_xor(a1, off);
                    a2 += __shfl_xor(a2, off); a3 += __shfl_xor(a3, off);
                }
                if (js == 0) {
                    f16x4 ov; ov[0] = (f16)a0; ov[1] = (f16)a1; ov[2] = (f16)a2; ov[3] = (f16)a3;
                    *(f16x4*)(o_lds + cb) = ov;
                }
            }
            __syncthreads();

            // ---- attn proj: 16 col-octets x 32 k-splits (k-chunk 4) ----
            {
                const int cg2 = lane & 1, ks = lane >> 1;
                const int cb = (wid * 2 + cg2) * 8, kp0 = ks * 2;
                f16x4 ov = *(const f16x4*)(o_lds + ks * 4);
                f16x2 o0 = {ov[0], ov[1]}, o1 = {ov[2], ov[3]};
                const f16x2* W = Wp2 + (size_t)l * (64 * DD);
                float acc[8] = {0,0,0,0,0,0,0,0};
                {
                    const f16x2* p = W + (size_t)kp0 * DD + cb;
                    f16x8 wa = *(const f16x8*)p;
                    f16x8 wb = *(const f16x8*)(p + 4);
                    dot8(acc, o0, wa, wb);
                }
                {
                    const f16x2* p = W + (size_t)(kp0 + 1) * DD + cb;
                    f16x8 wa = *(const f16x8*)p;
                    f16x8 wb = *(const f16x8*)(p + 4);
                    dot8(acc, o1, wa, wb);
                }
                #pragma unroll
                for (int off = 2; off <= 32; off <<= 1) {
                    #pragma unroll
                    for (int j = 0; j < 8; j++) acc[j] += __shfl_xor(acc[j], off);
                }
                if (ks == 0) {
                    #pragma unroll
                    for (int j = 0; j < 8; j++) x[cb + j] += acc[j] + c_projb[l][cb + j];
                }
            }
            __syncthreads();

            // ---- fc (LN2 fused) + gelu: 8 waves, 8 cols x 16 k ----
            {
                const int cg = lane & 7, ks = lane >> 3;
                const int cb = wid * 64 + cg * 8, k0 = ks * 16, kp0 = ks * 8;
                float m, rs; ln_stats(x, lane, m, rs);
                f16x2 hp[8]; make_h2(hp, x, c_ln2w[l], c_ln2b[l], k0, m, rs);
                const f16x2* W = Wf2u + (size_t)l * (64 * D4);
                float acc[8] = {0,0,0,0,0,0,0,0};
                #pragma unroll
                for (int t = 0; t < 8; t++) {
                    const f16x2* p = W + (size_t)(kp0 + t) * D4 + cb;
                    f16x8 wa = *(const f16x8*)p;
                    f16x8 wb = *(const f16x8*)(p + 4);
                    dot8(acc, hp[t], wa, wb);
                }
                #pragma unroll
                for (int off = 8; off <= 32; off <<= 1) {
                    #pragma unroll
                    for (int j = 0; j < 8; j++) acc[j] += __shfl_xor(acc[j], off);
                }
                if (ks == 0) {
                    f16x8 pk;
                    #pragma unroll
                    for (int j = 0; j < 8; j++) pk[j] = (f16)gelu_tanh(acc[j] + c_fcb[l][cb + j]);
                    *(f16x8*)(hm_lds + cb) = pk;
                }
            }
            __syncthreads();

            // ---- fc2: 16 col-octets x 32 k-splits (k-chunk 16) ----
            {
                const int cg2 = lane & 1, ks = lane >> 1;
                const int cb = (wid * 2 + cg2) * 8, k0 = ks * 16, kp0 = ks * 8;
                f16x8 ha = *(const f16x8*)(hm_lds + k0);
                f16x8 hbv = *(const f16x8*)(hm_lds + k0 + 8);
                const f16x2* W = Wg2 + (size_t)l * (256 * DD);
                float acc[8] = {0,0,0,0,0,0,0,0};
                #pragma unroll
                for (int t = 0; t < 8; t++) {
                    f16x2 hp = (t < 4) ? (f16x2){ha[2*t], ha[2*t+1]}
                                       : (f16x2){hbv[2*(t-4)], hbv[2*(t-4)+1]};
                    const f16x2* p = W + (size_t)(kp0 + t) * DD + cb;
                    f16x8 wa = *(const f16x8*)p;
                    f16x8 wb = *(const f16x8*)(p + 4);
                    dot8(acc, hp, wa, wb);
                }
                #pragma unroll
                for (int off = 2; off <= 32; off <<= 1) {
                    #pragma unroll
                    for (int j = 0; j < 8; j++) acc[j] += __shfl_xor(acc[j], off);
                }
                if (ks == 0) {
                    #pragma unroll
                    for (int j = 0; j < 8; j++) x[cb + j] += acc[j] + c_fc2b[l][cb + j];
                }
            }
            __syncthreads();
        } // layers

        // ---- final LN (fused) + head + state update ----
        {
            float m, rs; ln_stats(x, lane, m, rs);
            if (wid == 0) {
                float h0 = (x[lane]      - m) * rs * c_lnfw[lane]      + c_lnfb[lane];
                float h1 = (x[lane + 64] - m) * rs * c_lnfw[lane + 64] + c_lnfb[lane + 64];
                float v = wave_xor_sum(h0 * c_headw[lane] + h1 * c_headw[lane + 64]);
                if (lane == 0) {
                    float un = v + hb;
                    Y[b * TH + i] = s;
                    s_state = s + (-p0 * s + p1 * tanhf(un));
                    u_state = un;
                }
            }
        }
        __syncthreads();
    } // steps
}

extern "C" void kernel_launch(void* const* d_in, const int* in_sizes, int n_in,
                              void* d_out, int out_size, void* d_ws, size_t ws_size,
                              hipStream_t stream) {
    const float* data   = (const float*)d_in[0];
    const float* r      = (const float*)d_in[1];
    const float* wte_w  = (const float*)d_in[2];
    const float* wte_b  = (const float*)d_in[3];
    const float* wpe    = (const float*)d_in[4];
    const float* ln1_w  = (const float*)d_in[5];
    const float* ln1_b  = (const float*)d_in[6];
    const float* ln2_w  = (const float*)d_in[7];
    const float* ln2_b  = (const float*)d_in[8];
    const float* qkv_w  = (const float*)d_in[9];
    const float* qkv_b  = (const float*)d_in[10];
    const float* proj_w = (const float*)d_in[11];
    const float* proj_b = (const float*)d_in[12];
    const float* fc_w   = (const float*)d_in[13];
    const float* fc_b   = (const float*)d_in[14];
    const float* fc2_w  = (const float*)d_in[15];
    const float* fc2_b  = (const float*)d_in[16];
    const float* lnf_w  = (const float*)d_in[17];
    const float* lnf_b  = (const float*)d_in[18];
    const float* head_w = (const float*)d_in[19];
    const float* head_b = (const float*)d_in[20];

    f16* wsp = (f16*)d_ws;
    f16* Wall = wsp;                                    // (UQ+UP+UF+UF2) f16x2 units
    f16* Kc   = Wall + 2 * (size_t)(UQ + UP + UF + UF2);
    f16* Vc   = Kc + (size_t)NB * NL * TCAP * DD;

    const int n_units = UQ + UP + UF + UF2;
    prep_kernel<<<(n_units + 255) / 256, 256, 0, stream>>>(qkv_w, proj_w, fc_w, fc2_w, Wall);

    gpt_loop<<<NB, 512, 0, stream>>>(
        data, r, wte_w, wte_b, wpe, ln1_w, ln1_b, ln2_w, ln2_b,
        qkv_b, proj_b, fc_b, fc2_b, lnf_w, lnf_b, head_w, head_b,
        Wall, Kc, Vc, (float*)d_out);
}